// Round 1
// baseline (129.536 us; speedup 1.0000x reference)
//
#include <hip/hip_runtime.h>

#define B_ 4
#define S_ 512
#define T_ 512
#define D_ 256

#define K2F 2.8853900817779268f   // 2*log2(e), so exp2(x*K2F) = e^(2x)

// ---------------------------------------------------------------------------
// Kernel 1: fused linear + exp transform.
// Computes ya[r][j] = exp2((source@W_src + b_src)*K2F) for rows 0..2047,
// and yc likewise for target rows. Blocks 0..127 -> source, 128..255 -> target.
// 16 rows/block, 256 threads, thread = 4 rows x 4 cols register tile.
// ---------------------------------------------------------------------------
__global__ __launch_bounds__(256) void lin_exp_kernel(
    const float* __restrict__ src, const float* __restrict__ tgt,
    const float* __restrict__ Wsrc, const float* __restrict__ bsrc,
    const float* __restrict__ Wtgt, const float* __restrict__ btgt,
    float* __restrict__ ya, float* __restrict__ yc)
{
    __shared__ float inT[D_ * 20];   // [k][row], stride 20 (16 rows + pad), 20 KB
    __shared__ float Wl[32 * D_];    // [kk][col], 32 KB

    const int tid = threadIdx.x;
    const int nsrc_rows = B_ * S_;   // 2048
    const int r0 = blockIdx.x * 16;
    const bool is_tgt = (r0 >= nsrc_rows);
    const float* in   = is_tgt ? tgt  : src;
    const float* W    = is_tgt ? Wtgt : Wsrc;
    const float* bias = is_tgt ? btgt : bsrc;
    float* out        = is_tgt ? yc   : ya;
    const int rbase   = is_tgt ? (r0 - nsrc_rows) : r0;

    // Stage 16 input rows transposed: inT[k*20 + r] = in[rbase+r][k]
    {
        const int row = tid & 15;
        #pragma unroll
        for (int it = 0; it < 4; it++) {
            int kslot = it * 16 + (tid >> 4);   // 0..63
            int k4 = kslot * 4;
            float4 v = *(const float4*)&in[(rbase + row) * D_ + k4];
            inT[(k4 + 0) * 20 + row] = v.x;
            inT[(k4 + 1) * 20 + row] = v.y;
            inT[(k4 + 2) * 20 + row] = v.z;
            inT[(k4 + 3) * 20 + row] = v.w;
        }
    }

    const int rg = tid >> 6;   // wave id 0..3 -> rows 4*rg..4*rg+3
    const int cg = tid & 63;   // cols 4*cg..4*cg+3
    float acc[4][4];
    #pragma unroll
    for (int i = 0; i < 4; i++)
        #pragma unroll
        for (int j = 0; j < 4; j++) acc[i][j] = 0.f;

    for (int c0 = 0; c0 < D_; c0 += 32) {
        __syncthreads();   // protect Wl from previous chunk's readers (also covers inT on iter 0)
        // stage W chunk: Wl[kk][j] = W[c0+kk][j]
        #pragma unroll
        for (int it = 0; it < 8; it++) {
            int flat4 = it * 256 + tid;          // 0..2047 float4s
            int wrow  = flat4 >> 6;              // 0..31
            int wcol4 = (flat4 & 63) * 4;
            *(float4*)&Wl[wrow * D_ + wcol4] =
                *(const float4*)&W[(c0 + wrow) * D_ + wcol4];
        }
        __syncthreads();
        #pragma unroll 8
        for (int kk = 0; kk < 32; kk++) {
            float4 av = *(const float4*)&inT[(c0 + kk) * 20 + 4 * rg];  // broadcast
            float4 wv = *(const float4*)&Wl[kk * D_ + 4 * cg];
            acc[0][0] = fmaf(av.x, wv.x, acc[0][0]);
            acc[0][1] = fmaf(av.x, wv.y, acc[0][1]);
            acc[0][2] = fmaf(av.x, wv.z, acc[0][2]);
            acc[0][3] = fmaf(av.x, wv.w, acc[0][3]);
            acc[1][0] = fmaf(av.y, wv.x, acc[1][0]);
            acc[1][1] = fmaf(av.y, wv.y, acc[1][1]);
            acc[1][2] = fmaf(av.y, wv.z, acc[1][2]);
            acc[1][3] = fmaf(av.y, wv.w, acc[1][3]);
            acc[2][0] = fmaf(av.z, wv.x, acc[2][0]);
            acc[2][1] = fmaf(av.z, wv.y, acc[2][1]);
            acc[2][2] = fmaf(av.z, wv.z, acc[2][2]);
            acc[2][3] = fmaf(av.z, wv.w, acc[2][3]);
            acc[3][0] = fmaf(av.w, wv.x, acc[3][0]);
            acc[3][1] = fmaf(av.w, wv.y, acc[3][1]);
            acc[3][2] = fmaf(av.w, wv.z, acc[3][2]);
            acc[3][3] = fmaf(av.w, wv.w, acc[3][3]);
        }
    }

    // Epilogue: + bias, *K2F, exp2, store
    float4 bj = *(const float4*)&bias[4 * cg];
    #pragma unroll
    for (int i = 0; i < 4; i++) {
        float4 o;
        o.x = __builtin_amdgcn_exp2f((acc[i][0] + bj.x) * K2F);
        o.y = __builtin_amdgcn_exp2f((acc[i][1] + bj.y) * K2F);
        o.z = __builtin_amdgcn_exp2f((acc[i][2] + bj.z) * K2F);
        o.w = __builtin_amdgcn_exp2f((acc[i][3] + bj.w) * K2F);
        *(float4*)&out[(rbase + 4 * rg + i) * D_ + 4 * cg] = o;
    }
}

// ---------------------------------------------------------------------------
// Kernel 2: genP[b,t,s] = (sum_d w_d + b_res) - 2 * sum_d w_d / (1 + ya*yc)
// Tile 64t x 64s per block, 512 threads, thread = 2t x 4s accumulators.
// D chunked by 64 through LDS (transposed [k][row] layout, stride 68).
// ---------------------------------------------------------------------------
#define STR 68
__global__ __launch_bounds__(512) void genp_kernel(
    const float* __restrict__ ya, const float* __restrict__ yc,
    const float* __restrict__ Wres, const float* __restrict__ bres,
    float* __restrict__ out)
{
    __shared__ float la[64 * STR];   // [k][s]
    __shared__ float lc[64 * STR];   // [k][t]
    __shared__ float wl[D_];
    __shared__ float c0s;

    const int tid = threadIdx.x;
    const int s0 = blockIdx.x * 64;
    const int t0 = blockIdx.y * 64;
    const int b  = blockIdx.z;

    if (tid < D_) wl[tid] = Wres[tid];
    __syncthreads();
    if (tid == 0) {
        float s = bres[0];
        for (int d = 0; d < D_; d++) s += wl[d];
        c0s = s;
    }

    const float* abase = ya + (b * S_ + s0) * D_;
    const float* cbase = yc + (b * T_ + t0) * D_;

    const int m = tid & 15;   // s-group: s = s0 + 4m..4m+3
    const int g = tid >> 4;   // t-group 0..31: t = t0 + 2g..2g+1
    float acc[2][4] = {{0.f, 0.f, 0.f, 0.f}, {0.f, 0.f, 0.f, 0.f}};

    for (int d0 = 0; d0 < D_; d0 += 64) {
        __syncthreads();   // previous chunk's compute done before overwrite
        {
            const int k4  = (tid & 15) * 4;
            const int row = tid >> 4;         // 0..31
            #pragma unroll
            for (int it = 0; it < 2; it++) {
                int r = row + it * 32;
                float4 v = *(const float4*)&abase[r * D_ + d0 + k4];
                la[(k4 + 0) * STR + r] = v.x;
                la[(k4 + 1) * STR + r] = v.y;
                la[(k4 + 2) * STR + r] = v.z;
                la[(k4 + 3) * STR + r] = v.w;
                float4 u = *(const float4*)&cbase[r * D_ + d0 + k4];
                lc[(k4 + 0) * STR + r] = u.x;
                lc[(k4 + 1) * STR + r] = u.y;
                lc[(k4 + 2) * STR + r] = u.z;
                lc[(k4 + 3) * STR + r] = u.w;
            }
        }
        __syncthreads();
        #pragma unroll 4
        for (int k = 0; k < 64; k++) {
            float4 av = *(const float4*)&la[k * STR + 4 * m];
            float2 cv = *(const float2*)&lc[k * STR + 2 * g];
            float w = wl[d0 + k];
            float r00 = __builtin_amdgcn_rcpf(fmaf(cv.x, av.x, 1.f));
            float r01 = __builtin_amdgcn_rcpf(fmaf(cv.x, av.y, 1.f));
            float r02 = __builtin_amdgcn_rcpf(fmaf(cv.x, av.z, 1.f));
            float r03 = __builtin_amdgcn_rcpf(fmaf(cv.x, av.w, 1.f));
            float r10 = __builtin_amdgcn_rcpf(fmaf(cv.y, av.x, 1.f));
            float r11 = __builtin_amdgcn_rcpf(fmaf(cv.y, av.y, 1.f));
            float r12 = __builtin_amdgcn_rcpf(fmaf(cv.y, av.z, 1.f));
            float r13 = __builtin_amdgcn_rcpf(fmaf(cv.y, av.w, 1.f));
            acc[0][0] = fmaf(w, r00, acc[0][0]);
            acc[0][1] = fmaf(w, r01, acc[0][1]);
            acc[0][2] = fmaf(w, r02, acc[0][2]);
            acc[0][3] = fmaf(w, r03, acc[0][3]);
            acc[1][0] = fmaf(w, r10, acc[1][0]);
            acc[1][1] = fmaf(w, r11, acc[1][1]);
            acc[1][2] = fmaf(w, r12, acc[1][2]);
            acc[1][3] = fmaf(w, r13, acc[1][3]);
        }
    }

    const float C0 = c0s;
    #pragma unroll
    for (int i = 0; i < 2; i++) {
        int t = t0 + 2 * g + i;
        float4 o;
        o.x = C0 - 2.f * acc[i][0];
        o.y = C0 - 2.f * acc[i][1];
        o.z = C0 - 2.f * acc[i][2];
        o.w = C0 - 2.f * acc[i][3];
        *(float4*)&out[(b * T_ + t) * S_ + s0 + 4 * m] = o;
    }
}

// ---------------------------------------------------------------------------
// Kernel 3: prob = softmax(target @ W_prob + b_prob) over 2 classes.
// One wave per (b,t) row; 4 waves/block.
// ---------------------------------------------------------------------------
__global__ __launch_bounds__(256) void prob_kernel(
    const float* __restrict__ tgt, const float* __restrict__ Wp,
    const float* __restrict__ bp, float* __restrict__ out)
{
    const int row  = blockIdx.x * 4 + (threadIdx.x >> 6);
    const int lane = threadIdx.x & 63;
    float p0 = 0.f, p1 = 0.f;
    #pragma unroll
    for (int i = 0; i < 4; i++) {
        int d = lane + i * 64;
        float v = tgt[row * D_ + d];
        float2 w = *(const float2*)&Wp[d * 2];
        p0 = fmaf(v, w.x, p0);
        p1 = fmaf(v, w.y, p1);
    }
    #pragma unroll
    for (int off = 32; off > 0; off >>= 1) {
        p0 += __shfl_down(p0, off, 64);
        p1 += __shfl_down(p1, off, 64);
    }
    if (lane == 0) {
        const float L2E = 1.4426950408889634f;
        float l0 = p0 + bp[0], l1 = p1 + bp[1];
        float e10 = __builtin_amdgcn_exp2f((l1 - l0) * L2E);
        float e01 = __builtin_amdgcn_exp2f((l0 - l1) * L2E);
        float q0 = __builtin_amdgcn_rcpf(1.f + e10);
        float q1 = __builtin_amdgcn_rcpf(1.f + e01);
        out[B_ * T_ * S_ + row * 2 + 0] = q0;
        out[B_ * T_ * S_ + row * 2 + 1] = q1;
    }
}

extern "C" void kernel_launch(void* const* d_in, const int* in_sizes, int n_in,
                              void* d_out, int out_size, void* d_ws, size_t ws_size,
                              hipStream_t stream) {
    const float* source = (const float*)d_in[0];
    const float* target = (const float*)d_in[1];
    const float* W_src  = (const float*)d_in[2];
    const float* b_src  = (const float*)d_in[3];
    const float* W_tgt  = (const float*)d_in[4];
    const float* b_tgt  = (const float*)d_in[5];
    const float* W_res  = (const float*)d_in[6];
    const float* b_res  = (const float*)d_in[7];
    const float* W_prob = (const float*)d_in[8];
    const float* b_prob = (const float*)d_in[9];
    float* out = (float*)d_out;

    float* ya = (float*)d_ws;                 // B*S*D floats = 2 MB
    float* yc = ya + B_ * S_ * D_;            // B*T*D floats = 2 MB

    lin_exp_kernel<<<dim3((B_ * S_ + B_ * T_) / 16), 256, 0, stream>>>(
        source, target, W_src, b_src, W_tgt, b_tgt, ya, yc);
    genp_kernel<<<dim3(S_ / 64, T_ / 64, B_), 512, 0, stream>>>(
        ya, yc, W_res, b_res, out);
    prob_kernel<<<dim3(B_ * T_ / 4), 256, 0, stream>>>(
        target, W_prob, b_prob, out);
}